// Round 1
// baseline (1087.737 us; speedup 1.0000x reference)
//
#include <hip/hip_runtime.h>
#include <math.h>

#define NN 4096
#define NITER 20

// exp of a double argument with fp32 exp + first-order fp64 correction:
// exp(x) = expf(xf) * (1 + (x - xf)), error ~ expf's ~1ulp (random, averages out in sums)
__device__ __forceinline__ double exp_hi(double x) {
    float xf = (float)x;
    double dl = x - (double)xf;
    double e = (double)expf(xf);
    return fma(e, dl, e);
}

__global__ void k_init(double* buf, int n) {
    int i = blockIdx.x * blockDim.x + threadIdx.x;
    if (i < n) buf[i] = 0.0;
}

// C-step: colacc[j] += sum_i exp(W[i][j] - R[i]) for this block's row slab.
// grid = 1024 blocks: 64 column-groups x 16 row-slabs. block = 256 threads.
__global__ __launch_bounds__(256) void k_col(const float* __restrict__ W,
                                             const double* __restrict__ R,
                                             double* __restrict__ colacc) {
    const int g  = blockIdx.x >> 4;    // column group, 0..63
    const int s  = blockIdx.x & 15;    // row slab, 0..15 (256 rows each)
    const int jl = threadIdx.x & 63;   // lane -> consecutive columns (coalesced)
    const int wv = threadIdx.x >> 6;   // wave id in block, 0..3
    const int j  = g * 64 + jl;

    const float*  wp = W + (size_t)(s * 256 + wv) * NN + j;
    const double* rp = R + s * 256 + wv;

    double acc0 = 0.0, acc1 = 0.0;
    #pragma unroll 8
    for (int k = 0; k < 64; k += 2) {
        double ri0 = rp[k * 4];
        double ri1 = rp[(k + 1) * 4];
        float  w0  = wp[(size_t)k * 4 * NN];
        float  w1  = wp[(size_t)(k + 1) * 4 * NN];
        acc0 += exp_hi((double)w0 - ri0);
        acc1 += exp_hi((double)w1 - ri1);
    }
    double acc = acc0 + acc1;

    __shared__ double sdata[256];
    sdata[threadIdx.x] = acc;
    __syncthreads();
    if (threadIdx.x < 64) {
        double sum = sdata[threadIdx.x] + sdata[threadIdx.x + 64]
                   + sdata[threadIdx.x + 128] + sdata[threadIdx.x + 192];
        unsafeAtomicAdd(&colacc[j], sum);  // HW global_atomic_add_f64; 16 adds/address
    }
}

// R-step: R[i] = log( sum_j exp(W[i][j] - C[j]) ), C[j] = log(colacc[j]).
// grid = 256 blocks x 1024 threads; one wave per row, 16 rows/block.
__global__ __launch_bounds__(1024) void k_row(const float* __restrict__ W,
                                              const double* __restrict__ colacc,
                                              double* __restrict__ R) {
    __shared__ double Cl[NN];  // 32 KiB
    for (int j = threadIdx.x; j < NN; j += 1024)
        Cl[j] = log(colacc[j]);
    __syncthreads();

    const int wv = threadIdx.x >> 6;   // 0..15
    const int l  = threadIdx.x & 63;
    const int i  = blockIdx.x * 16 + wv;
    const float* wp = W + (size_t)i * NN;

    double acc = 0.0;
    #pragma unroll 4
    for (int k = 0; k < 64; ++k) {
        int j = k * 64 + l;            // coalesced 256B/wave
        acc += exp_hi((double)wp[j] - Cl[j]);
    }
    for (int off = 32; off > 0; off >>= 1)
        acc += __shfl_xor(acc, off, 64);
    if (l == 0) R[i] = log(acc);
}

// Final: P = exp(W - C - R); hard = one-hot(argmax_j of (W - C)), first-index ties.
__global__ __launch_bounds__(1024) void k_final(const float* __restrict__ W,
                                                const double* __restrict__ colacc,
                                                const double* __restrict__ R,
                                                float* __restrict__ P,
                                                float* __restrict__ H) {
    __shared__ double Cl[NN];
    for (int j = threadIdx.x; j < NN; j += 1024)
        Cl[j] = log(colacc[j]);
    __syncthreads();

    const int wv = threadIdx.x >> 6;
    const int l  = threadIdx.x & 63;
    const int i  = blockIdx.x * 16 + wv;
    const float* wp = W + (size_t)i * NN;
    float* pp = P + (size_t)i * NN;
    float* hp = H + (size_t)i * NN;
    const double ri = R[i];

    double besty = -1e300;
    int bestj = 0;
    #pragma unroll 4
    for (int k = 0; k < 64; ++k) {
        int j = k * 64 + l;
        double y = (double)wp[j] - Cl[j] - ri;
        pp[j] = expf((float)y);
        if (y > besty) { besty = y; bestj = j; }  // strict > keeps first index in-lane
    }
    for (int off = 32; off > 0; off >>= 1) {
        double oy = __shfl_xor(besty, off, 64);
        int    oj = __shfl_xor(bestj, off, 64);
        if (oy > besty || (oy == besty && oj < bestj)) { besty = oy; bestj = oj; }
    }
    #pragma unroll 4
    for (int k = 0; k < 64; ++k) {
        int j = k * 64 + l;
        hp[j] = (j == bestj) ? 1.0f : 0.0f;
    }
}

extern "C" void kernel_launch(void* const* d_in, const int* in_sizes, int n_in,
                              void* d_out, int out_size, void* d_ws, size_t ws_size,
                              hipStream_t stream) {
    const float* W = (const float*)d_in[0];
    float* out0 = (float*)d_out;                  // P_hat
    float* out1 = out0 + (size_t)NN * NN;         // P_hat_hard (== one-hot numerically)

    double* R      = (double*)d_ws;               // NN doubles
    double* colacc = R + NN;                      // NITER * NN doubles (per-iter buffers)

    const int ztotal = NN + NITER * NN;           // zero R + all colacc buffers
    k_init<<<(ztotal + 255) / 256, 256, 0, stream>>>(R, ztotal);

    for (int t = 0; t < NITER; ++t) {
        double* acc_t = colacc + (size_t)t * NN;
        k_col<<<1024, 256, 0, stream>>>(W, R, acc_t);
        k_row<<<256, 1024, 0, stream>>>(W, acc_t, R);
    }
    k_final<<<256, 1024, 0, stream>>>(W, colacc + (size_t)(NITER - 1) * NN, R, out0, out1);
}

// Round 2
// 707.353 us; speedup vs baseline: 1.5378x; 1.5378x over previous
//
#include <hip/hip_runtime.h>
#include <math.h>

#define NN 4096
#define NITER 20

// exp of a double argument with fp32 exp + first-order fp64 correction.
__device__ __forceinline__ double exp_hi(double x) {
    float xf = (float)x;
    double dl = x - (double)xf;
    double e = (double)expf(xf);
    return fma(e, dl, e);
}

// u = 1 (R_0 = 0), colacc[NITER][NN] = 0.
__global__ void k_init(double* u, double* colacc) {
    int i = blockIdx.x * blockDim.x + threadIdx.x;
    if (i < NN) u[i] = 1.0;
    if (i < NITER * NN) colacc[i] = 0.0;
}

// E = exp(W), fp32, float4-vectorized.
__global__ __launch_bounds__(256) void k_exp(const float* __restrict__ W,
                                             float* __restrict__ E) {
    size_t i = (size_t)(blockIdx.x * blockDim.x + threadIdx.x) * 4;
    float4 w = *(const float4*)(W + i);
    float4 e;
    e.x = (float)exp_hi((double)w.x);
    e.y = (float)exp_hi((double)w.y);
    e.z = (float)exp_hi((double)w.z);
    e.w = (float)exp_hi((double)w.w);
    *(float4*)(E + i) = e;
}

// Column pass: colacc[j] += sum_i E[i][j] * u[i].
// grid = 1024: 16 col-groups (256 cols) x 64 row-slabs (64 rows). block = 256.
__global__ __launch_bounds__(256) void k_colv(const float* __restrict__ E,
                                              const double* __restrict__ u,
                                              double* __restrict__ colacc) {
    const int l  = threadIdx.x & 63;
    const int wv = threadIdx.x >> 6;
    const int g  = blockIdx.x & 15;    // column group
    const int s  = blockIdx.x >> 4;    // row slab

    const float4* ep = (const float4*)(E + (size_t)(s * 64 + wv) * NN + g * 256) + l;
    const double* up = u + s * 64 + wv;

    double a0 = 0.0, a1 = 0.0, a2 = 0.0, a3 = 0.0;
    #pragma unroll
    for (int k = 0; k < 16; ++k) {
        float4 e = ep[(size_t)k * 4 * (NN / 4)];   // rows s*64 + wv + 4k, coalesced 1KB/wave
        double uu = up[k * 4];                      // wave-uniform broadcast
        a0 = fma((double)e.x, uu, a0);
        a1 = fma((double)e.y, uu, a1);
        a2 = fma((double)e.z, uu, a2);
        a3 = fma((double)e.w, uu, a3);
    }

    __shared__ double sdata[1024];
    const int t = threadIdx.x;
    sdata[t * 4 + 0] = a0;
    sdata[t * 4 + 1] = a1;
    sdata[t * 4 + 2] = a2;
    sdata[t * 4 + 3] = a3;
    __syncthreads();
    if (t < 256) {
        // col offset t: entries at wv*256 + t
        double ssum = sdata[t] + sdata[256 + t] + sdata[512 + t] + sdata[768 + t];
        unsafeAtomicAdd(&colacc[g * 256 + t], ssum);  // fp64 HW atomic, 64 adds/address
    }
}

// Row pass: u[i] = 1 / sum_j E[i][j] * v[j],  v[j] = 1/colacc[j] (fp32 in LDS).
// grid = 256 x 1024; one wave per row.
__global__ __launch_bounds__(1024) void k_rowu(const float* __restrict__ E,
                                               const double* __restrict__ colacc,
                                               double* __restrict__ u) {
    __shared__ float v[NN];  // 16 KiB
    for (int j = threadIdx.x; j < NN; j += 1024)
        v[j] = (float)(1.0 / colacc[j]);
    __syncthreads();

    const int l  = threadIdx.x & 63;
    const int wv = threadIdx.x >> 6;
    const int i  = blockIdx.x * 16 + wv;
    const float4* ep = (const float4*)(E + (size_t)i * NN) + l;
    const float4* vp = (const float4*)v + l;

    double a0 = 0.0, a1 = 0.0, a2 = 0.0, a3 = 0.0;
    #pragma unroll
    for (int k = 0; k < 16; ++k) {
        float4 e  = ep[k * 64];    // j = k*256 + 4l .. +3, coalesced 1KB/wave
        float4 vv = vp[k * 64];    // ds_read_b128, conflict-free
        a0 = fma((double)e.x, (double)vv.x, a0);
        a1 = fma((double)e.y, (double)vv.y, a1);
        a2 = fma((double)e.z, (double)vv.z, a2);
        a3 = fma((double)e.w, (double)vv.w, a3);
    }
    double acc = (a0 + a1) + (a2 + a3);
    for (int off = 32; off > 0; off >>= 1)
        acc += __shfl_xor(acc, off, 64);
    if (l == 0) u[i] = 1.0 / acc;
}

// Final: P = exp(W + lv[j] + lu[i]); hard = one-hot(argmax_j (W + lv[j])).
__global__ __launch_bounds__(1024) void k_final(const float* __restrict__ W,
                                                const double* __restrict__ colacc,
                                                const double* __restrict__ u,
                                                float* __restrict__ P,
                                                float* __restrict__ H) {
    __shared__ double lv[NN];  // 32 KiB
    for (int j = threadIdx.x; j < NN; j += 1024)
        lv[j] = -log(colacc[j]);
    __syncthreads();

    const int l  = threadIdx.x & 63;
    const int wv = threadIdx.x >> 6;
    const int i  = blockIdx.x * 16 + wv;
    const float4* wp = (const float4*)(W + (size_t)i * NN) + l;
    float4* pp = (float4*)(P + (size_t)i * NN) + l;
    float4* hp = (float4*)(H + (size_t)i * NN) + l;
    const double lu = log(u[i]);   // = -R[i]

    double besty = -1e300;
    int bestj = 0;
    #pragma unroll 4
    for (int k = 0; k < 16; ++k) {
        float4 w = wp[k * 64];
        int jb = k * 256 + l * 4;
        double y0 = (double)w.x + lv[jb + 0];
        double y1 = (double)w.y + lv[jb + 1];
        double y2 = (double)w.z + lv[jb + 2];
        double y3 = (double)w.w + lv[jb + 3];
        float4 pv;
        pv.x = expf((float)(y0 + lu));
        pv.y = expf((float)(y1 + lu));
        pv.z = expf((float)(y2 + lu));
        pv.w = expf((float)(y3 + lu));
        pp[k * 64] = pv;
        if (y0 > besty) { besty = y0; bestj = jb + 0; }   // strict > keeps first index
        if (y1 > besty) { besty = y1; bestj = jb + 1; }
        if (y2 > besty) { besty = y2; bestj = jb + 2; }
        if (y3 > besty) { besty = y3; bestj = jb + 3; }
    }
    for (int off = 32; off > 0; off >>= 1) {
        double oy = __shfl_xor(besty, off, 64);
        int    oj = __shfl_xor(bestj, off, 64);
        if (oy > besty || (oy == besty && oj < bestj)) { besty = oy; bestj = oj; }
    }
    #pragma unroll 4
    for (int k = 0; k < 16; ++k) {
        int jb = k * 256 + l * 4;
        float4 hv;
        hv.x = (jb + 0 == bestj) ? 1.0f : 0.0f;
        hv.y = (jb + 1 == bestj) ? 1.0f : 0.0f;
        hv.z = (jb + 2 == bestj) ? 1.0f : 0.0f;
        hv.w = (jb + 3 == bestj) ? 1.0f : 0.0f;
        hp[k * 64] = hv;
    }
}

extern "C" void kernel_launch(void* const* d_in, const int* in_sizes, int n_in,
                              void* d_out, int out_size, void* d_ws, size_t ws_size,
                              hipStream_t stream) {
    const float* W = (const float*)d_in[0];
    float* out0 = (float*)d_out;                  // P_hat
    float* out1 = out0 + (size_t)NN * NN;         // P_hat_hard (== one-hot numerically)

    float*  E      = (float*)d_ws;                        // NN*NN fp32 (64 MiB)
    double* u      = (double*)(E + (size_t)NN * NN);      // NN fp64
    double* colacc = u + NN;                              // NITER*NN fp64

    k_init<<<(NITER * NN + 255) / 256, 256, 0, stream>>>(u, colacc);
    k_exp<<<(NN * NN / 4 + 255) / 256, 256, 0, stream>>>(W, E);

    for (int t = 0; t < NITER; ++t) {
        double* acc_t = colacc + (size_t)t * NN;
        k_colv<<<1024, 256, 0, stream>>>(E, u, acc_t);
        k_rowu<<<256, 1024, 0, stream>>>(E, acc_t, u);
    }
    k_final<<<256, 1024, 0, stream>>>(W, colacc + (size_t)(NITER - 1) * NN, u, out0, out1);
}